// Round 4
// baseline (205.141 us; speedup 1.0000x reference)
//
#include <hip/hip_runtime.h>

// One-level separable wavelet filterbank (maxflat), periodic extension.
// x: [8,3,1024,1024] f32 -> out: [4, 8,3,512,512] f32 (LL, LH, HL, HH)
//
// Round 7: direct dataflow kernel — NO LDS, NO barriers.
// Rounds 3-6 post-mortem: all two-phase LDS variants plateau at ~67 us
// with every pipe <50% (hbm 34%, VALU 12%, occ 40%); traffic cuts don't
// move time -> the barrier/LDS-round-trip critical path is the limiter.
// Here each thread computes 8 output cols x 1 row x 4 subbands directly:
// 42 independent float4 loads (2-row register double buffer), row filter
// + column accumulation entirely in registers. Only dependence is the
// FMA accumulator chain; redundant neighbor loads hit L1/L2.

constexpr int H = 1024, W = 1024;
constexpr int NIMG = 24;            // 8*3
constexpr int HOUT = 512, WOUT = 512;
constexpr int BROWS = 32;           // output rows per block
constexpr int BCOLS = 64;           // output cols per block (8 groups of 8)

__global__ __launch_bounds__(256)
void wfb_kernel(const float* __restrict__ x, float* __restrict__ out) {
    // h (len 5, ext 2) and h1 (len 7, ext 4), exact maxflat values
    const float h0c[5] = {0.125f, 0.35355339059327373f, 1.25f,
                          0.35355339059327373f, 0.125f};
    const float h1c[7] = {0.025888347648318447f,  0.07322330470336313f,
                          -0.06878156646177083f, -0.8535533905932737f,
                          -0.06878156646177083f,  0.07322330470336313f,
                          0.025888347648318447f};

    const int tid = threadIdx.x;
    const int img = blockIdx.z;
    const int R  = blockIdx.y * BROWS + (tid >> 3);       // global output row
    const int J0 = blockIdx.x * BCOLS + (tid & 7) * 8;    // first of 8 out cols
    const float* __restrict__ xin = x + (size_t)img * H * W;

    const int rb = 2 * R - 4;        // first input row (7 needed: rb..rb+6)
    const int cb = 2 * J0 - 4;       // first input col (21 used, 24 loaded)
                                     // cb % 4 == 0 -> float4-aligned

    float LL[8] = {0,0,0,0,0,0,0,0}, LH[8] = {0,0,0,0,0,0,0,0};
    float HL[8] = {0,0,0,0,0,0,0,0}, HH[8] = {0,0,0,0,0,0,0,0};

    auto LOADROW = [&](int d, float* v) {
        const int gr = (rb + d) & (H - 1);                // periodic rows
        const float* __restrict__ rowp = xin + (size_t)gr * W;
        #pragma unroll
        for (int q = 0; q < 6; ++q) {
            int gc = (cb + 4 * q) & (W - 1);              // periodic, 16B-align
            float4 f = *(const float4*)(rowp + gc);
            v[4*q + 0] = f.x; v[4*q + 1] = f.y;
            v[4*q + 2] = f.z; v[4*q + 3] = f.w;
        }
    };

    // row-filter input row d, then accumulate its column-filter contribution.
    // LH/HH use h1c[d] (7-tap, d=0..6); LL/HL use h0c[d-2] (5-tap, d=2..6).
    auto STEP = [&](int d, const float* v) {
        #pragma unroll
        for (int u = 0; u < 8; ++u) {
            const float* p = v + 2 * u;
            float Lr = h0c[0]*p[2] + h0c[1]*p[3] + h0c[2]*p[4]
                     + h0c[3]*p[5] + h0c[4]*p[6];
            float Hr = h1c[0]*p[0] + h1c[1]*p[1] + h1c[2]*p[2] + h1c[3]*p[3]
                     + h1c[4]*p[4] + h1c[5]*p[5] + h1c[6]*p[6];
            LH[u] += h1c[d] * Lr;
            HH[u] += h1c[d] * Hr;
            if (d >= 2) {
                LL[u] += h0c[d-2] * Lr;
                HL[u] += h0c[d-2] * Hr;
            }
        }
    };

    // ---- 2-deep register double buffer over the 7 input rows ----
    float va[24], vb[24];
    LOADROW(0, va);
    LOADROW(1, vb);
    STEP(0, va);  LOADROW(2, va);
    STEP(1, vb);  LOADROW(3, vb);
    STEP(2, va);  LOADROW(4, va);
    STEP(3, vb);  LOADROW(5, vb);
    STEP(4, va);  LOADROW(6, va);
    STEP(5, vb);
    STEP(6, va);

    // ---- stores: 2 float4 per subband ----
    constexpr size_t SB = (size_t)NIMG * HOUT * WOUT;     // per-subband stride
    float* __restrict__ o = out + (size_t)img * HOUT * WOUT;
    const size_t off = (size_t)R * WOUT + J0;
    *(float4*)(o + 0*SB + off)     = make_float4(LL[0], LL[1], LL[2], LL[3]);
    *(float4*)(o + 0*SB + off + 4) = make_float4(LL[4], LL[5], LL[6], LL[7]);
    *(float4*)(o + 1*SB + off)     = make_float4(LH[0], LH[1], LH[2], LH[3]);
    *(float4*)(o + 1*SB + off + 4) = make_float4(LH[4], LH[5], LH[6], LH[7]);
    *(float4*)(o + 2*SB + off)     = make_float4(HL[0], HL[1], HL[2], HL[3]);
    *(float4*)(o + 2*SB + off + 4) = make_float4(HL[4], HL[5], HL[6], HL[7]);
    *(float4*)(o + 3*SB + off)     = make_float4(HH[0], HH[1], HH[2], HH[3]);
    *(float4*)(o + 3*SB + off + 4) = make_float4(HH[4], HH[5], HH[6], HH[7]);
}

extern "C" void kernel_launch(void* const* d_in, const int* in_sizes, int n_in,
                              void* d_out, int out_size, void* d_ws, size_t ws_size,
                              hipStream_t stream) {
    const float* x = (const float*)d_in[0];
    float* out = (float*)d_out;
    dim3 grid(WOUT / BCOLS, HOUT / BROWS, NIMG);   // 8 x 16 x 24
    wfb_kernel<<<grid, dim3(256), 0, stream>>>(x, out);
}